// Round 13
// baseline (462.768 us; speedup 1.0000x reference)
//
#include <hip/hip_runtime.h>
#include <hip/hip_bf16.h>

#define NN 50000
#define NE 600000
#define IND 16
#define EDD 8
#define HIDD 128
#define NH 4
#define CC 32
#define EMBD 64
#define FEATD 64
#define NB_SCAN ((NN + 255) / 256)  // 196

typedef __hip_bfloat16 bf16;
typedef __attribute__((ext_vector_type(8))) short bshort8;
typedef __attribute__((ext_vector_type(4))) float floatx4;

// round-to-nearest-even f32 -> bf16 bits
__device__ __forceinline__ unsigned short f2bu(float f) {
    unsigned int u = __float_as_uint(f);
    u += 0x7fffu + ((u >> 16) & 1u);
    return (unsigned short)(u >> 16);
}

template <bool F32>
__device__ __forceinline__ float LD(const void* p, long long i) {
    if constexpr (F32) return ((const float*)p)[i];
    else return __bfloat162float(((const bf16*)p)[i]);
}

// ---- zero cnt + deg
__global__ void k_init0(int* __restrict__ cnt, int* __restrict__ deg) {
    int i = blockIdx.x * blockDim.x + threadIdx.x;
    if (i == 0) *cnt = 0;
    if (i < NN) deg[i] = 0;
}

__device__ __forceinline__ bool is_f32(const int* cnt) { return *cnt > 8; }

// ---- CSR histogram + per-edge rank; blocks 0..63 also run the dtype detector
// (fp32 misread as bf16 shows ~2^-8 rate of exp==0xFF halfwords; bf16 data: 0)
__global__ void k_histdet(const int* __restrict__ ei, int* __restrict__ deg,
                          int* __restrict__ rank, const unsigned short* __restrict__ x,
                          int nhalf, int* __restrict__ cnt) {
    int e = blockIdx.x * blockDim.x + threadIdx.x;
    if (e < NE) rank[e] = atomicAdd(&deg[ei[NE + e]], 1);
    if (blockIdx.x < 64) {
        __shared__ int c;
        if (threadIdx.x == 0) c = 0;
        __syncthreads();
        int hits = 0;
        for (int i = blockIdx.x * 256 + threadIdx.x; i < nhalf; i += 64 * 256)
            if ((x[i] & 0x7F80u) == 0x7F80u) hits++;
        if (hits) atomicAdd(&c, hits);
        __syncthreads();
        if (threadIdx.x == 0 && c) atomicAdd(cnt, c);
    }
}

// level 1: per-tile exclusive scan + block totals + WINDOW-LOCAL degree-sorted perm
__global__ void k_scan1(const int* __restrict__ deg, int* __restrict__ off,
                        int* __restrict__ bsum, int* __restrict__ perm) {
    __shared__ int tile[256];
    __shared__ int lh[64];
    __shared__ int lb[64];
    int t = threadIdx.x;
    int gid = blockIdx.x * 256 + t;
    if (t < 64) lh[t] = 0;
    __syncthreads();
    int v = (gid < NN) ? deg[gid] : 0;
    int b = min(v, 63);
    int lr = 0;
    if (gid < NN) lr = atomicAdd(&lh[b], 1);
    tile[t] = v;
    __syncthreads();
    if (t < 64) lb[t] = lh[t];
    __syncthreads();
    #pragma unroll
    for (int o = 1; o < 64; o <<= 1) {
        int u = (t >= o && t < 64) ? lb[t - o] : 0;
        __syncthreads();
        if (t < 64) lb[t] += u;
        __syncthreads();
    }
    #pragma unroll
    for (int o = 1; o < 256; o <<= 1) {
        int u = (t >= o) ? tile[t - o] : 0;
        __syncthreads();
        tile[t] += u;
        __syncthreads();
    }
    if (gid < NN) {
        off[gid] = tile[t] - v;
        perm[blockIdx.x * 256 + (lb[b] - lh[b]) + lr] = gid;  // window-local rank
    }
    if (t == 255) bsum[blockIdx.x] = tile[255];
}
// level 2: scan the 196 block sums -> exclusive
__global__ void k_scan2(int* __restrict__ bsum) {
    __shared__ int tile[256];
    int t = threadIdx.x;
    int v = (t < NB_SCAN) ? bsum[t] : 0;
    tile[t] = v;
    __syncthreads();
    #pragma unroll
    for (int o = 1; o < 256; o <<= 1) {
        int u = (t >= o) ? tile[t - o] : 0;
        __syncthreads();
        tile[t] += u;
        __syncthreads();
    }
    if (t < NB_SCAN) bsum[t] = tile[t] - v;
}
// level 3: finalize off
__global__ void k_scan3(int* __restrict__ off, const int* __restrict__ bsum) {
    int gid = blockIdx.x * 256 + threadIdx.x;
    if (gid < NN) off[gid] += bsum[blockIdx.x];
    if (gid == 0) off[NN] = NE;
}

// slot = off[dst] + rank[e] -> esrc + packed bf16 edge_attr, CSR-sorted. No atomics.
// Thread 0 also writes the pad slot (index NE) used by unconditional prefetch.
template <bool F32>
__device__ void fill_impl(const int* __restrict__ ei, const int* __restrict__ off,
                          const int* __restrict__ rank, int* __restrict__ esrc,
                          uint4* __restrict__ ea8, const void* ea) {
    int e = blockIdx.x * blockDim.x + threadIdx.x;
    if (e >= NE) return;
    if (e == 0) {
        esrc[NE] = 0;
        uint4 z; z.x = 0; z.y = 0; z.z = 0; z.w = 0;
        ea8[NE] = z;
    }
    int slot = off[ei[NE + e]] + rank[e];
    esrc[slot] = ei[e];
    unsigned int w[4];
    #pragma unroll
    for (int d = 0; d < 4; d++) {
        unsigned int lo = f2bu(LD<F32>(ea, (long long)e * EDD + 2 * d));
        unsigned int hi = f2bu(LD<F32>(ea, (long long)e * EDD + 2 * d + 1));
        w[d] = lo | (hi << 16);
    }
    uint4 v; v.x = w[0]; v.y = w[1]; v.z = w[2]; v.w = w[3];
    ea8[slot] = v;
}
__global__ void k_fill(const int* cnt, const int* ei, const int* off, const int* rank,
                       int* esrc, uint4* ea8, const void* ea) {
    if (is_f32(cnt)) fill_impl<true>(ei, off, rank, esrc, ea8, ea);
    else             fill_impl<false>(ei, off, rank, esrc, ea8, ea);
}

// ---- merged: build_z (blocks 0..NN-1) + weight prep (blocks NN..NN+511)
template <bool F32>
__device__ void bzpw_impl(const void* x, const int* __restrict__ node_idx, const void* emb,
                          const void* W_in, const void* b_in, bf16* __restrict__ zb,
                          const void* Wl1, const void* bl1, const void* Wr1, const void* br1,
                          const void* Wl2, const void* bl2, const void* Wr2, const void* br2,
                          bf16* __restrict__ wbT, float* __restrict__ bias) {
    int t = threadIdx.x;  // 128
    if (blockIdx.x < NN) {
        int n = blockIdx.x;
        float val;
        if (t < FEATD) {
            float acc = LD<F32>(b_in, t);
            #pragma unroll
            for (int k = 0; k < IND; k++)
                acc += LD<F32>(x, (long long)n * IND + k) * LD<F32>(W_in, k * FEATD + t);
            val = fmaxf(acc, 0.f);
        } else {
            val = LD<F32>(emb, (long long)node_idx[n] * EMBD + (t - FEATD));
        }
        zb[n * HIDD + t] = __float2bfloat16(val);
    } else {
        int bid = blockIdx.x - NN;
        int layer = bid >> 8;
        int n = bid & 255;
        const void* W = layer ? (n < HIDD ? Wl2 : Wr2) : (n < HIDD ? Wl1 : Wr1);
        const void* b = layer ? (n < HIDD ? bl2 : br2) : (n < HIDD ? bl1 : br1);
        int nn = n & (HIDD - 1);
        wbT[(layer * 256 + n) * HIDD + t] = __float2bfloat16(LD<F32>(W, t * HIDD + nn));
        if (t == 0) bias[layer * 256 + n] = LD<F32>(b, nn);
    }
}
__global__ void k_bzpw(const int* cnt, const void* x, const int* node_idx, const void* emb,
                       const void* W_in, const void* b_in, bf16* zb,
                       const void* Wl1, const void* bl1, const void* Wr1, const void* br1,
                       const void* Wl2, const void* bl2, const void* Wr2, const void* br2,
                       bf16* wbT, float* bias) {
    if (is_f32(cnt)) bzpw_impl<true>(x, node_idx, emb, W_in, b_in, zb, Wl1, bl1, Wr1, br1,
                                     Wl2, bl2, Wr2, br2, wbT, bias);
    else             bzpw_impl<false>(x, node_idx, emb, W_in, b_in, zb, Wl1, bl1, Wr1, br1,
                                      Wl2, bl2, Wr2, br2, wbT, bias);
}

// ---- MFMA projection: [xl|xr] = zb @ wbT^T + bias. 32-row M-tile per block
// (1563 blocks => ~6/CU), both A-subtiles' loads issued before the MFMA chain.
__global__ __launch_bounds__(256) void k_projmm(const bf16* __restrict__ zb,
                                                const bf16* __restrict__ wbT,
                                                const float* __restrict__ bias,
                                                bf16* __restrict__ xl, bf16* __restrict__ xr) {
    int wave = threadIdx.x >> 6, lane = threadIdx.x & 63;
    int m0 = blockIdx.x * 32;
    int n0 = wave * 64;
    int l15 = lane & 15, q = lane >> 4;
    bshort8 bfr[4][4];  // [j][s]
    #pragma unroll
    for (int j = 0; j < 4; j++)
        #pragma unroll
        for (int s = 0; s < 4; s++)
            bfr[j][s] = *(const bshort8*)(wbT + ((n0 + j * 16 + l15) << 7) + s * 32 + q * 8);
    float bv[4];
    #pragma unroll
    for (int j = 0; j < 4; j++) bv[j] = bias[n0 + j * 16 + l15];
    // A loads for both 16-row subtiles (reads past row NN land in ws scratch; stores guarded)
    const bf16* arow0 = zb + ((m0 + l15) << 7) + q * 8;
    const bf16* arow1 = arow0 + (16 << 7);
    bshort8 a0[4], a1[4];
    #pragma unroll
    for (int s = 0; s < 4; s++) a0[s] = *(const bshort8*)(arow0 + s * 32);
    #pragma unroll
    for (int s = 0; s < 4; s++) a1[s] = *(const bshort8*)(arow1 + s * 32);
    #pragma unroll
    for (int mi = 0; mi < 2; mi++) {
        floatx4 acc0 = {0.f, 0.f, 0.f, 0.f}, acc1 = acc0, acc2 = acc0, acc3 = acc0;
        #pragma unroll
        for (int s = 0; s < 4; s++) {
            bshort8 a = mi ? a1[s] : a0[s];
            acc0 = __builtin_amdgcn_mfma_f32_16x16x32_bf16(a, bfr[0][s], acc0, 0, 0, 0);
            acc1 = __builtin_amdgcn_mfma_f32_16x16x32_bf16(a, bfr[1][s], acc1, 0, 0, 0);
            acc2 = __builtin_amdgcn_mfma_f32_16x16x32_bf16(a, bfr[2][s], acc2, 0, 0, 0);
            acc3 = __builtin_amdgcn_mfma_f32_16x16x32_bf16(a, bfr[3][s], acc3, 0, 0, 0);
        }
        floatx4 accs[4] = {acc0, acc1, acc2, acc3};
        #pragma unroll
        for (int j = 0; j < 4; j++) {
            int colg = n0 + j * 16 + l15;
            bf16* dst = (colg < HIDD) ? (xl + colg) : (xr + (colg - HIDD));
            #pragma unroll
            for (int r = 0; r < 4; r++) {
                int rowc = m0 + mi * 16 + q * 4 + r;
                if (rowc < NN) dst[rowc << 7] = __float2bfloat16(accs[j][r] + bv[j]);
            }
        }
    }
}

// ---- fused GAT layer: 2 nodes per wave (window-local degree-matched via perm),
// 4 ch/lane, unconditional pad-backed prefetch, 32-bit addressing, barrier-free LN.
// LAST fuses the output head.
template <bool F32, bool LAST>
__device__ void gat_impl(const int* __restrict__ perm,
                         const int* __restrict__ off, const int* __restrict__ esrc,
                         const uint4* __restrict__ ea8,
                         const void* We, const void* be, const void* att,
                         const bf16* __restrict__ xl, const bf16* __restrict__ xr,
                         const void* bo, bf16* __restrict__ zb,
                         const void* g, const void* beta,
                         const void* Wo, const void* bout, void* out) {
    int wave = threadIdx.x >> 6;
    int half = (threadIdx.x >> 5) & 1;
    int lane5 = threadIdx.x & 31;
    int n = perm[blockIdx.x * 8 + wave * 2 + half];
    int c0 = lane5 << 2;  // 4 channels c0..c0+3 ; head = lane5>>3
    float wv[EDD][4], at[4], bev[4];
    #pragma unroll
    for (int d = 0; d < EDD; d++)
        #pragma unroll
        for (int j = 0; j < 4; j++) wv[d][j] = LD<F32>(We, d * HIDD + c0 + j);
    #pragma unroll
    for (int j = 0; j < 4; j++) {
        at[j] = LD<F32>(att, c0 + j);
        bev[j] = LD<F32>(be, c0 + j);
    }
    uint2 xru = *(const uint2*)(xr + (n << 7) + c0);
    float xrv[4];
    xrv[0] = __uint_as_float(xru.x << 16);
    xrv[1] = __uint_as_float(xru.x & 0xffff0000u);
    xrv[2] = __uint_as_float(xru.y << 16);
    xrv[3] = __uint_as_float(xru.y & 0xffff0000u);
    int lo = off[n], hi = off[n + 1];
    float acc[4] = {0.f, 0.f, 0.f, 0.f};
    float den = 0.f;
    if (lo < hi) {
        int src = esrc[lo];
        uint4 eu = ea8[lo];
        uint2 xu = *(const uint2*)(xl + (src << 7) + c0);
        for (int i = lo; i < hi; i++) {
            int src_n = esrc[i + 1];        // pad slot at NE keeps this in-bounds
            uint4 eu_n = ea8[i + 1];
            uint2 xu_n = *(const uint2*)(xl + (src_n << 7) + c0);
            float e[8];
            e[0] = __uint_as_float(eu.x << 16); e[1] = __uint_as_float(eu.x & 0xffff0000u);
            e[2] = __uint_as_float(eu.y << 16); e[3] = __uint_as_float(eu.y & 0xffff0000u);
            e[4] = __uint_as_float(eu.z << 16); e[5] = __uint_as_float(eu.z & 0xffff0000u);
            e[6] = __uint_as_float(eu.w << 16); e[7] = __uint_as_float(eu.w & 0xffff0000u);
            float xv[4];
            xv[0] = __uint_as_float(xu.x << 16);
            xv[1] = __uint_as_float(xu.x & 0xffff0000u);
            xv[2] = __uint_as_float(xu.y << 16);
            xv[3] = __uint_as_float(xu.y & 0xffff0000u);
            float ls = 0.f;
            #pragma unroll
            for (int j = 0; j < 4; j++) {
                float ee = bev[j];
                #pragma unroll
                for (int d = 0; d < EDD; d++) ee += e[d] * wv[d][j];
                float s = xv[j] + xrv[j] + ee;
                s = fmaxf(s, 0.2f * s);  // leakyrelu
                ls += s * at[j];
            }
            ls += __shfl_xor(ls, 1);
            ls += __shfl_xor(ls, 2);
            ls += __shfl_xor(ls, 4);   // 8-lane head group = 32 channels
            float ex = __expf(ls);
            #pragma unroll
            for (int j = 0; j < 4; j++) acc[j] += ex * xv[j];
            den += ex;
            src = src_n; eu = eu_n; xu = xu_n;
        }
    }
    float inv = (den > 0.f) ? 1.0f / den : 0.f;
    uint2 zu = *(const uint2*)(zb + (n << 7) + c0);
    float zv[4];
    zv[0] = __uint_as_float(zu.x << 16);
    zv[1] = __uint_as_float(zu.x & 0xffff0000u);
    zv[2] = __uint_as_float(zu.y << 16);
    zv[3] = __uint_as_float(zu.y & 0xffff0000u);
    float v[4];
    float s = 0.f;
    #pragma unroll
    for (int j = 0; j < 4; j++) {
        float hv = fmaxf(acc[j] * inv + LD<F32>(bo, c0 + j), 0.f);
        v[j] = zv[j] + hv;
        s += v[j];
    }
    #pragma unroll
    for (int m = 16; m; m >>= 1) s += __shfl_xor(s, m);  // 32-lane sum
    float mu = s * (1.f / HIDD);
    float s2 = 0.f;
    float dv[4];
    #pragma unroll
    for (int j = 0; j < 4; j++) { dv[j] = v[j] - mu; s2 += dv[j] * dv[j]; }
    #pragma unroll
    for (int m = 16; m; m >>= 1) s2 += __shfl_xor(s2, m);
    float rs = rsqrtf(s2 * (1.f / HIDD) + 1e-5f);
    float o[4];
    #pragma unroll
    for (int j = 0; j < 4; j++)
        o[j] = dv[j] * rs * LD<F32>(g, c0 + j) + LD<F32>(beta, c0 + j);
    if constexpr (!LAST) {
        uint2 pk;
        pk.x = (unsigned int)f2bu(o[0]) | ((unsigned int)f2bu(o[1]) << 16);
        pk.y = (unsigned int)f2bu(o[2]) | ((unsigned int)f2bu(o[3]) << 16);
        *(uint2*)(zb + (n << 7) + c0) = pk;
    } else {
        float po = 0.f;
        #pragma unroll
        for (int j = 0; j < 4; j++) po += o[j] * LD<F32>(Wo, c0 + j);
        #pragma unroll
        for (int m = 16; m; m >>= 1) po += __shfl_xor(po, m);
        if (lane5 == 0) {
            float r = po + LD<F32>(bout, 0);
            if constexpr (F32) ((float*)out)[n] = r;
            else               ((bf16*)out)[n] = __float2bfloat16(r);
        }
    }
}
__global__ void k_gat(const int* cnt, const int* perm, const int* off, const int* esrc,
                      const uint4* ea8, const void* We, const void* be, const void* att,
                      const bf16* xl, const bf16* xr, const void* bo, bf16* zb,
                      const void* g, const void* beta) {
    if (is_f32(cnt)) gat_impl<true, false>(perm, off, esrc, ea8, We, be, att, xl, xr, bo, zb, g, beta, nullptr, nullptr, nullptr);
    else             gat_impl<false, false>(perm, off, esrc, ea8, We, be, att, xl, xr, bo, zb, g, beta, nullptr, nullptr, nullptr);
}
__global__ void k_gat_last(const int* cnt, const int* perm, const int* off, const int* esrc,
                           const uint4* ea8, const void* We, const void* be, const void* att,
                           const bf16* xl, const bf16* xr, const void* bo, bf16* zb,
                           const void* g, const void* beta,
                           const void* Wo, const void* bout, void* out) {
    if (is_f32(cnt)) gat_impl<true, true>(perm, off, esrc, ea8, We, be, att, xl, xr, bo, zb, g, beta, Wo, bout, out);
    else             gat_impl<false, true>(perm, off, esrc, ea8, We, be, att, xl, xr, bo, zb, g, beta, Wo, bout, out);
}

extern "C" void kernel_launch(void* const* d_in, const int* in_sizes, int n_in,
                              void* d_out, int out_size, void* d_ws, size_t ws_size,
                              hipStream_t stream) {
    const void* x        = d_in[0];
    const int*  node_idx = (const int*)d_in[1];
    const int*  ei       = (const int*)d_in[2];
    const void* ea       = d_in[3];
    const void* emb      = d_in[4];
    const void* W_in     = d_in[5];
    const void* b_in     = d_in[6];
    const void* Wl1 = d_in[7];  const void* bl1 = d_in[8];
    const void* Wr1 = d_in[9];  const void* br1 = d_in[10];
    const void* We1 = d_in[11]; const void* be1 = d_in[12];
    const void* att1 = d_in[13]; const void* bo1 = d_in[14];
    const void* Wl2 = d_in[15]; const void* bl2 = d_in[16];
    const void* Wr2 = d_in[17]; const void* br2 = d_in[18];
    const void* We2 = d_in[19]; const void* be2 = d_in[20];
    const void* att2 = d_in[21]; const void* bo2 = d_in[22];
    const void* g1 = d_in[23]; const void* beta1 = d_in[24];
    const void* g2 = d_in[25]; const void* beta2 = d_in[26];
    const void* W_out = d_in[27]; const void* b_out = d_in[28];

    // workspace (~54 MB), 16B-aligned sections:
    int*   cnt   = (int*)d_ws;                             // 64 ints
    uint4* ea8   = (uint4*)((char*)d_ws + 256);            // NE+4 (pad slot at NE)
    bf16*  zb    = (bf16*)(ea8 + NE + 4);                  // NN*HIDD
    bf16*  xl    = zb + NN * HIDD;                         // NN*HIDD
    bf16*  xr    = xl + NN * HIDD;                         // NN*HIDD
    bf16*  wbT   = xr + NN * HIDD;                         // 2*256*128
    float* bias  = (float*)(wbT + 2 * 256 * HIDD);         // 512
    int*   off   = (int*)(bias + 512);                     // NN+1
    int*   deg   = off + NN + 1;                           // NN
    int*   rank  = deg + NN;                               // NE
    int*   perm  = rank + NE;                              // NN
    int*   esrc  = perm + NN;                              // NE+4 (pad at NE)
    int*   bsum  = esrc + NE + 4;                          // 256

    int nhalf = in_sizes[0] < 65536 ? in_sizes[0] : 65536;
    k_init0<<<(NN + 255) / 256, 256, 0, stream>>>(cnt, deg);
    k_histdet<<<(NE + 255) / 256, 256, 0, stream>>>(ei, deg, rank,
                                                    (const unsigned short*)x, nhalf, cnt);
    k_scan1<<<NB_SCAN, 256, 0, stream>>>(deg, off, bsum, perm);
    k_scan2<<<1, 256, 0, stream>>>(bsum);
    k_scan3<<<NB_SCAN, 256, 0, stream>>>(off, bsum);
    k_bzpw<<<NN + 512, HIDD, 0, stream>>>(cnt, x, node_idx, emb, W_in, b_in, zb,
                                          Wl1, bl1, Wr1, br1, Wl2, bl2, Wr2, br2, wbT, bias);
    k_fill<<<(NE + 255) / 256, 256, 0, stream>>>(cnt, ei, off, rank, esrc, ea8, ea);

    // ---- layer 1 ----
    k_projmm<<<(NN + 31) / 32, 256, 0, stream>>>(zb, wbT, bias, xl, xr);
    k_gat<<<NN / 8, 256, 0, stream>>>(cnt, perm, off, esrc, ea8, We1, be1, att1, xl, xr, bo1, zb, g1, beta1);

    // ---- layer 2 ----
    k_projmm<<<(NN + 31) / 32, 256, 0, stream>>>(zb, wbT + 256 * HIDD, bias + 256, xl, xr);
    k_gat_last<<<NN / 8, 256, 0, stream>>>(cnt, perm, off, esrc, ea8, We2, be2, att2, xl, xr, bo2, zb,
                                           g2, beta2, W_out, b_out, d_out);
}

// Round 14
// 402.777 us; speedup vs baseline: 1.1489x; 1.1489x over previous
//
#include <hip/hip_runtime.h>
#include <hip/hip_bf16.h>

#define NN 50000
#define NE 600000
#define IND 16
#define EDD 8
#define HIDD 128
#define NH 4
#define CC 32
#define EMBD 64
#define FEATD 64
#define NB_SCAN ((NN + 255) / 256)  // 196

typedef __hip_bfloat16 bf16;
typedef __attribute__((ext_vector_type(8))) short bshort8;
typedef __attribute__((ext_vector_type(4))) float floatx4;

// round-to-nearest-even f32 -> bf16 bits
__device__ __forceinline__ unsigned short f2bu(float f) {
    unsigned int u = __float_as_uint(f);
    u += 0x7fffu + ((u >> 16) & 1u);
    return (unsigned short)(u >> 16);
}

template <bool F32>
__device__ __forceinline__ float LD(const void* p, long long i) {
    if constexpr (F32) return ((const float*)p)[i];
    else return __bfloat162float(((const bf16*)p)[i]);
}

__device__ __forceinline__ bool is_f32(const int* cnt) { return *cnt > 8; }

// ---- merged: dtype detect (block 0, LDS reduce, no atomics) + zero deg/dcnt
__global__ void k_detinit(const unsigned short* __restrict__ x, int nhalf,
                          int* __restrict__ cnt, int* __restrict__ deg,
                          int* __restrict__ dcnt) {
    if (blockIdx.x == 0) {
        __shared__ int red[256];
        int hits = 0;
        for (int i = threadIdx.x; i < nhalf; i += 256)
            if ((x[i] & 0x7F80u) == 0x7F80u) hits++;
        red[threadIdx.x] = hits;
        __syncthreads();
        for (int o = 128; o; o >>= 1) {
            if (threadIdx.x < o) red[threadIdx.x] += red[threadIdx.x + o];
            __syncthreads();
        }
        if (threadIdx.x == 0) *cnt = red[0];
    } else {
        int gid = (blockIdx.x - 1) * 256 + threadIdx.x;
        if (gid < NN) deg[gid] = 0;
        if (blockIdx.x == 1 && threadIdx.x < 64) dcnt[threadIdx.x] = 0;
    }
}

// ---- CSR: histogram also records each edge's rank within its dst bucket
__global__ void k_hist(const int* __restrict__ ei, int* __restrict__ deg, int* __restrict__ rank) {
    int e = blockIdx.x * blockDim.x + threadIdx.x;
    if (e < NE) rank[e] = atomicAdd(&deg[ei[NE + e]], 1);
}

// level 1: per-tile exclusive scan + block totals + degree-bucket local histogram
__global__ void k_scan1(const int* __restrict__ deg, int* __restrict__ off,
                        int* __restrict__ bsum, int* __restrict__ dcnt,
                        int* __restrict__ rankd) {
    __shared__ int tile[256];
    __shared__ int lh[64];
    __shared__ int lbase[64];
    int t = threadIdx.x;
    int gid = blockIdx.x * 256 + t;
    if (t < 64) lh[t] = 0;
    __syncthreads();
    int v = (gid < NN) ? deg[gid] : 0;
    int b = min(v, 63);
    int lr = 0;
    if (gid < NN) lr = atomicAdd(&lh[b], 1);
    tile[t] = v;
    __syncthreads();
    if (t < 64) lbase[t] = lh[t] ? atomicAdd(&dcnt[t], lh[t]) : 0;
    #pragma unroll
    for (int o = 1; o < 256; o <<= 1) {
        int u = (t >= o) ? tile[t - o] : 0;
        __syncthreads();
        tile[t] += u;
        __syncthreads();
    }
    if (gid < NN) {
        off[gid] = tile[t] - v;
        rankd[gid] = lbase[b] + lr;
    }
    if (t == 255) bsum[blockIdx.x] = tile[255];
}
// level 2: scan block sums (196) and degree buckets (64), both exclusive
__global__ void k_scan2(int* __restrict__ bsum, int* __restrict__ dcnt,
                        int* __restrict__ dbase) {
    __shared__ int tile[256];
    __shared__ int d2[64];
    int t = threadIdx.x;
    int v = (t < NB_SCAN) ? bsum[t] : 0;
    tile[t] = v;
    int dv = (t < 64) ? dcnt[t] : 0;
    if (t < 64) d2[t] = dv;
    __syncthreads();
    #pragma unroll
    for (int o = 1; o < 256; o <<= 1) {
        int u = (t >= o) ? tile[t - o] : 0;
        __syncthreads();
        tile[t] += u;
        __syncthreads();
    }
    #pragma unroll
    for (int o = 1; o < 64; o <<= 1) {
        int u = (t >= o && t < 64) ? d2[t - o] : 0;
        __syncthreads();
        if (t < 64) d2[t] += u;
        __syncthreads();
    }
    if (t < NB_SCAN) bsum[t] = tile[t] - v;
    if (t < 64) dbase[t] = d2[t] - dv;
}
// level 3: finalize off; scatter degree-sorted node permutation
__global__ void k_scan3(int* __restrict__ off, const int* __restrict__ bsum,
                        const int* __restrict__ deg, const int* __restrict__ rankd,
                        const int* __restrict__ dbase, int* __restrict__ perm) {
    int gid = blockIdx.x * 256 + threadIdx.x;
    if (gid < NN) {
        off[gid] += bsum[blockIdx.x];
        int b = min(deg[gid], 63);
        perm[dbase[b] + rankd[gid]] = gid;
    }
    if (gid == 0) off[NN] = NE;
}

// slot = off[dst] + rank[e] -> esrc + packed bf16 edge_attr, CSR-sorted. No atomics.
// Threads 0..5 zero the pad slots (NE..NE+5) used by unconditional deep prefetch.
template <bool F32>
__device__ void fill_impl(const int* __restrict__ ei, const int* __restrict__ off,
                          const int* __restrict__ rank, int* __restrict__ esrc,
                          uint4* __restrict__ ea8, const void* ea) {
    int e = blockIdx.x * blockDim.x + threadIdx.x;
    if (e >= NE) return;
    if (e < 6) {
        esrc[NE + e] = 0;
        uint4 z; z.x = 0; z.y = 0; z.z = 0; z.w = 0;
        ea8[NE + e] = z;
    }
    int slot = off[ei[NE + e]] + rank[e];
    esrc[slot] = ei[e];
    unsigned int w[4];
    #pragma unroll
    for (int d = 0; d < 4; d++) {
        unsigned int lo = f2bu(LD<F32>(ea, (long long)e * EDD + 2 * d));
        unsigned int hi = f2bu(LD<F32>(ea, (long long)e * EDD + 2 * d + 1));
        w[d] = lo | (hi << 16);
    }
    uint4 v; v.x = w[0]; v.y = w[1]; v.z = w[2]; v.w = w[3];
    ea8[slot] = v;
}
__global__ void k_fill(const int* cnt, const int* ei, const int* off, const int* rank,
                       int* esrc, uint4* ea8, const void* ea) {
    if (is_f32(cnt)) fill_impl<true>(ei, off, rank, esrc, ea8, ea);
    else             fill_impl<false>(ei, off, rank, esrc, ea8, ea);
}

// ---- merged: build_z (blocks 0..NN-1) + weight prep (blocks NN..NN+511)
template <bool F32>
__device__ void bzpw_impl(const void* x, const int* __restrict__ node_idx, const void* emb,
                          const void* W_in, const void* b_in, bf16* __restrict__ zb,
                          const void* Wl1, const void* bl1, const void* Wr1, const void* br1,
                          const void* Wl2, const void* bl2, const void* Wr2, const void* br2,
                          bf16* __restrict__ wbT, float* __restrict__ bias) {
    int t = threadIdx.x;  // 128
    if (blockIdx.x < NN) {
        int n = blockIdx.x;
        float val;
        if (t < FEATD) {
            float acc = LD<F32>(b_in, t);
            #pragma unroll
            for (int k = 0; k < IND; k++)
                acc += LD<F32>(x, (long long)n * IND + k) * LD<F32>(W_in, k * FEATD + t);
            val = fmaxf(acc, 0.f);
        } else {
            val = LD<F32>(emb, (long long)node_idx[n] * EMBD + (t - FEATD));
        }
        zb[n * HIDD + t] = __float2bfloat16(val);
    } else {
        int bid = blockIdx.x - NN;
        int layer = bid >> 8;
        int n = bid & 255;
        const void* W = layer ? (n < HIDD ? Wl2 : Wr2) : (n < HIDD ? Wl1 : Wr1);
        const void* b = layer ? (n < HIDD ? bl2 : br2) : (n < HIDD ? bl1 : br1);
        int nn = n & (HIDD - 1);
        wbT[(layer * 256 + n) * HIDD + t] = __float2bfloat16(LD<F32>(W, t * HIDD + nn));
        if (t == 0) bias[layer * 256 + n] = LD<F32>(b, nn);
    }
}
__global__ void k_bzpw(const int* cnt, const void* x, const int* node_idx, const void* emb,
                       const void* W_in, const void* b_in, bf16* zb,
                       const void* Wl1, const void* bl1, const void* Wr1, const void* br1,
                       const void* Wl2, const void* bl2, const void* Wr2, const void* br2,
                       bf16* wbT, float* bias) {
    if (is_f32(cnt)) bzpw_impl<true>(x, node_idx, emb, W_in, b_in, zb, Wl1, bl1, Wr1, br1,
                                     Wl2, bl2, Wr2, br2, wbT, bias);
    else             bzpw_impl<false>(x, node_idx, emb, W_in, b_in, zb, Wl1, bl1, Wr1, br1,
                                      Wl2, bl2, Wr2, br2, wbT, bias);
}

// ---- MFMA projection: [xl|xr] = zb @ wbT^T + bias. 32-row M-tile per block.
__global__ __launch_bounds__(256) void k_projmm(const bf16* __restrict__ zb,
                                                const bf16* __restrict__ wbT,
                                                const float* __restrict__ bias,
                                                bf16* __restrict__ xl, bf16* __restrict__ xr) {
    int wave = threadIdx.x >> 6, lane = threadIdx.x & 63;
    int m0 = blockIdx.x * 32;
    int n0 = wave * 64;
    int l15 = lane & 15, q = lane >> 4;
    bshort8 bfr[4][4];  // [j][s]
    #pragma unroll
    for (int j = 0; j < 4; j++)
        #pragma unroll
        for (int s = 0; s < 4; s++)
            bfr[j][s] = *(const bshort8*)(wbT + ((n0 + j * 16 + l15) << 7) + s * 32 + q * 8);
    float bv[4];
    #pragma unroll
    for (int j = 0; j < 4; j++) bv[j] = bias[n0 + j * 16 + l15];
    const bf16* arow0 = zb + ((m0 + l15) << 7) + q * 8;
    const bf16* arow1 = arow0 + (16 << 7);
    bshort8 a0[4], a1[4];
    #pragma unroll
    for (int s = 0; s < 4; s++) a0[s] = *(const bshort8*)(arow0 + s * 32);
    #pragma unroll
    for (int s = 0; s < 4; s++) a1[s] = *(const bshort8*)(arow1 + s * 32);
    #pragma unroll
    for (int mi = 0; mi < 2; mi++) {
        floatx4 acc0 = {0.f, 0.f, 0.f, 0.f}, acc1 = acc0, acc2 = acc0, acc3 = acc0;
        #pragma unroll
        for (int s = 0; s < 4; s++) {
            bshort8 a = mi ? a1[s] : a0[s];
            acc0 = __builtin_amdgcn_mfma_f32_16x16x32_bf16(a, bfr[0][s], acc0, 0, 0, 0);
            acc1 = __builtin_amdgcn_mfma_f32_16x16x32_bf16(a, bfr[1][s], acc1, 0, 0, 0);
            acc2 = __builtin_amdgcn_mfma_f32_16x16x32_bf16(a, bfr[2][s], acc2, 0, 0, 0);
            acc3 = __builtin_amdgcn_mfma_f32_16x16x32_bf16(a, bfr[3][s], acc3, 0, 0, 0);
        }
        floatx4 accs[4] = {acc0, acc1, acc2, acc3};
        #pragma unroll
        for (int j = 0; j < 4; j++) {
            int colg = n0 + j * 16 + l15;
            bf16* dst = (colg < HIDD) ? (xl + colg) : (xr + (colg - HIDD));
            #pragma unroll
            for (int r = 0; r < 4; r++) {
                int rowc = m0 + mi * 16 + q * 4 + r;
                if (rowc < NN) dst[rowc << 7] = __float2bfloat16(accs[j][r] + bv[j]);
            }
        }
    }
}

// ---- per-edge compute body (half-wave: 32 lanes, 4 ch/lane, 8-lane head groups)
__device__ __forceinline__ void edge_body(uint4 eu, uint2 xu, const float (*wv)[4],
                                          const float* bev, const float* at,
                                          const float* xrv, float mask,
                                          float* acc, float& den) {
    float e[8];
    e[0] = __uint_as_float(eu.x << 16); e[1] = __uint_as_float(eu.x & 0xffff0000u);
    e[2] = __uint_as_float(eu.y << 16); e[3] = __uint_as_float(eu.y & 0xffff0000u);
    e[4] = __uint_as_float(eu.z << 16); e[5] = __uint_as_float(eu.z & 0xffff0000u);
    e[6] = __uint_as_float(eu.w << 16); e[7] = __uint_as_float(eu.w & 0xffff0000u);
    float xv[4];
    xv[0] = __uint_as_float(xu.x << 16); xv[1] = __uint_as_float(xu.x & 0xffff0000u);
    xv[2] = __uint_as_float(xu.y << 16); xv[3] = __uint_as_float(xu.y & 0xffff0000u);
    float ls = 0.f;
    #pragma unroll
    for (int j = 0; j < 4; j++) {
        float ee = bev[j];
        #pragma unroll
        for (int d = 0; d < EDD; d++) ee += e[d] * wv[d][j];
        float s = xv[j] + xrv[j] + ee;
        s = fmaxf(s, 0.2f * s);  // leakyrelu
        ls += s * at[j];
    }
    ls += __shfl_xor(ls, 1);
    ls += __shfl_xor(ls, 2);
    ls += __shfl_xor(ls, 4);   // 8-lane head group = 32 channels
    float ex = __expf(ls) * mask;
    #pragma unroll
    for (int j = 0; j < 4; j++) acc[j] += ex * xv[j];
    den += ex;
}

// ---- fused GAT layer: 2 nodes per wave (degree-matched via global-sort perm),
// 4 ch/lane, 2-edge ILP with two-level rotating prefetch (xl one iter ahead,
// esrc/ea8 two iters ahead; pad slots NE..NE+5), barrier-free LN.
// LAST fuses the output head.
template <bool F32, bool LAST>
__device__ void gat_impl(const int* __restrict__ perm,
                         const int* __restrict__ off, const int* __restrict__ esrc,
                         const uint4* __restrict__ ea8,
                         const void* We, const void* be, const void* att,
                         const bf16* __restrict__ xl, const bf16* __restrict__ xr,
                         const void* bo, bf16* __restrict__ zb,
                         const void* g, const void* beta,
                         const void* Wo, const void* bout, void* out) {
    int wave = threadIdx.x >> 6;
    int half = (threadIdx.x >> 5) & 1;
    int lane5 = threadIdx.x & 31;
    int n = perm[blockIdx.x * 8 + wave * 2 + half];
    int c0 = lane5 << 2;  // 4 channels c0..c0+3 ; head = lane5>>3
    float wv[EDD][4], at[4], bev[4];
    #pragma unroll
    for (int d = 0; d < EDD; d++)
        #pragma unroll
        for (int j = 0; j < 4; j++) wv[d][j] = LD<F32>(We, d * HIDD + c0 + j);
    #pragma unroll
    for (int j = 0; j < 4; j++) {
        at[j] = LD<F32>(att, c0 + j);
        bev[j] = LD<F32>(be, c0 + j);
    }
    uint2 xru = *(const uint2*)(xr + (n << 7) + c0);
    float xrv[4];
    xrv[0] = __uint_as_float(xru.x << 16);
    xrv[1] = __uint_as_float(xru.x & 0xffff0000u);
    xrv[2] = __uint_as_float(xru.y << 16);
    xrv[3] = __uint_as_float(xru.y & 0xffff0000u);
    int lo = off[n], hi = off[n + 1];
    float accA[4] = {0.f, 0.f, 0.f, 0.f}, accB[4] = {0.f, 0.f, 0.f, 0.f};
    float denA = 0.f, denB = 0.f;
    if (lo < hi) {
        // edges i, i+1 fully loaded; edges i+2, i+3: src+ea loaded (xl issued in-loop)
        int sA = esrc[lo],      sB = esrc[lo + 1];
        uint4 eA = ea8[lo],     eB = ea8[lo + 1];
        uint2 xA = *(const uint2*)(xl + (sA << 7) + c0);
        uint2 xB = *(const uint2*)(xl + (sB << 7) + c0);
        int snA = esrc[lo + 2], snB = esrc[lo + 3];
        uint4 enA = ea8[lo + 2], enB = ea8[lo + 3];
        for (int i = lo; i < hi; i += 2) {
            uint2 xnA = *(const uint2*)(xl + (snA << 7) + c0);  // xl for i+2/i+3
            uint2 xnB = *(const uint2*)(xl + (snB << 7) + c0);
            int s2A = esrc[i + 4],  s2B = esrc[i + 5];          // meta for i+4/i+5
            uint4 e2A = ea8[i + 4], e2B = ea8[i + 5];
            edge_body(eA, xA, wv, bev, at, xrv, 1.f, accA, denA);
            float mB = (i + 1 < hi) ? 1.f : 0.f;
            edge_body(eB, xB, wv, bev, at, xrv, mB, accB, denB);
            eA = enA; eB = enB; xA = xnA; xB = xnB;
            snA = s2A; snB = s2B; enA = e2A; enB = e2B;
        }
        #pragma unroll
        for (int j = 0; j < 4; j++) accA[j] += accB[j];
        denA += denB;
    }
    float inv = (denA > 0.f) ? 1.0f / denA : 0.f;
    uint2 zu = *(const uint2*)(zb + (n << 7) + c0);
    float zv[4];
    zv[0] = __uint_as_float(zu.x << 16);
    zv[1] = __uint_as_float(zu.x & 0xffff0000u);
    zv[2] = __uint_as_float(zu.y << 16);
    zv[3] = __uint_as_float(zu.y & 0xffff0000u);
    float v[4];
    float s = 0.f;
    #pragma unroll
    for (int j = 0; j < 4; j++) {
        float hv = fmaxf(accA[j] * inv + LD<F32>(bo, c0 + j), 0.f);
        v[j] = zv[j] + hv;
        s += v[j];
    }
    #pragma unroll
    for (int m = 16; m; m >>= 1) s += __shfl_xor(s, m);  // 32-lane sum
    float mu = s * (1.f / HIDD);
    float s2 = 0.f;
    float dv[4];
    #pragma unroll
    for (int j = 0; j < 4; j++) { dv[j] = v[j] - mu; s2 += dv[j] * dv[j]; }
    #pragma unroll
    for (int m = 16; m; m >>= 1) s2 += __shfl_xor(s2, m);
    float rs = rsqrtf(s2 * (1.f / HIDD) + 1e-5f);
    float o[4];
    #pragma unroll
    for (int j = 0; j < 4; j++)
        o[j] = dv[j] * rs * LD<F32>(g, c0 + j) + LD<F32>(beta, c0 + j);
    if constexpr (!LAST) {
        uint2 pk;
        pk.x = (unsigned int)f2bu(o[0]) | ((unsigned int)f2bu(o[1]) << 16);
        pk.y = (unsigned int)f2bu(o[2]) | ((unsigned int)f2bu(o[3]) << 16);
        *(uint2*)(zb + (n << 7) + c0) = pk;
    } else {
        float po = 0.f;
        #pragma unroll
        for (int j = 0; j < 4; j++) po += o[j] * LD<F32>(Wo, c0 + j);
        #pragma unroll
        for (int m = 16; m; m >>= 1) po += __shfl_xor(po, m);
        if (lane5 == 0) {
            float r = po + LD<F32>(bout, 0);
            if constexpr (F32) ((float*)out)[n] = r;
            else               ((bf16*)out)[n] = __float2bfloat16(r);
        }
    }
}
__global__ void k_gat(const int* cnt, const int* perm, const int* off, const int* esrc,
                      const uint4* ea8, const void* We, const void* be, const void* att,
                      const bf16* xl, const bf16* xr, const void* bo, bf16* zb,
                      const void* g, const void* beta) {
    if (is_f32(cnt)) gat_impl<true, false>(perm, off, esrc, ea8, We, be, att, xl, xr, bo, zb, g, beta, nullptr, nullptr, nullptr);
    else             gat_impl<false, false>(perm, off, esrc, ea8, We, be, att, xl, xr, bo, zb, g, beta, nullptr, nullptr, nullptr);
}
__global__ void k_gat_last(const int* cnt, const int* perm, const int* off, const int* esrc,
                           const uint4* ea8, const void* We, const void* be, const void* att,
                           const bf16* xl, const bf16* xr, const void* bo, bf16* zb,
                           const void* g, const void* beta,
                           const void* Wo, const void* bout, void* out) {
    if (is_f32(cnt)) gat_impl<true, true>(perm, off, esrc, ea8, We, be, att, xl, xr, bo, zb, g, beta, Wo, bout, out);
    else             gat_impl<false, true>(perm, off, esrc, ea8, We, be, att, xl, xr, bo, zb, g, beta, Wo, bout, out);
}

extern "C" void kernel_launch(void* const* d_in, const int* in_sizes, int n_in,
                              void* d_out, int out_size, void* d_ws, size_t ws_size,
                              hipStream_t stream) {
    const void* x        = d_in[0];
    const int*  node_idx = (const int*)d_in[1];
    const int*  ei       = (const int*)d_in[2];
    const void* ea       = d_in[3];
    const void* emb      = d_in[4];
    const void* W_in     = d_in[5];
    const void* b_in     = d_in[6];
    const void* Wl1 = d_in[7];  const void* bl1 = d_in[8];
    const void* Wr1 = d_in[9];  const void* br1 = d_in[10];
    const void* We1 = d_in[11]; const void* be1 = d_in[12];
    const void* att1 = d_in[13]; const void* bo1 = d_in[14];
    const void* Wl2 = d_in[15]; const void* bl2 = d_in[16];
    const void* Wr2 = d_in[17]; const void* br2 = d_in[18];
    const void* We2 = d_in[19]; const void* be2 = d_in[20];
    const void* att2 = d_in[21]; const void* bo2 = d_in[22];
    const void* g1 = d_in[23]; const void* beta1 = d_in[24];
    const void* g2 = d_in[25]; const void* beta2 = d_in[26];
    const void* W_out = d_in[27]; const void* b_out = d_in[28];

    // workspace (~54 MB), 16B-aligned sections:
    int*   cnt   = (int*)d_ws;                             // 64 ints
    uint4* ea8   = (uint4*)((char*)d_ws + 256);            // NE+8 (pad slots at NE..)
    bf16*  zb    = (bf16*)(ea8 + NE + 8);                  // NN*HIDD
    bf16*  xl    = zb + NN * HIDD;                         // NN*HIDD
    bf16*  xr    = xl + NN * HIDD;                         // NN*HIDD
    bf16*  wbT   = xr + NN * HIDD;                         // 2*256*128
    float* bias  = (float*)(wbT + 2 * 256 * HIDD);         // 512
    int*   off   = (int*)(bias + 512);                     // NN+1
    int*   deg   = off + NN + 1;                           // NN
    int*   rank  = deg + NN;                               // NE
    int*   rankd = rank + NE;                              // NN
    int*   perm  = rankd + NN;                             // NN
    int*   esrc  = perm + NN;                              // NE+8 (pads at NE..)
    int*   bsum  = esrc + NE + 8;                          // 256
    int*   dcnt  = bsum + 256;                             // 64
    int*   dbase = dcnt + 64;                              // 64

    int nhalf = in_sizes[0] < 16384 ? in_sizes[0] : 16384;
    k_detinit<<<NB_SCAN + 1, 256, 0, stream>>>((const unsigned short*)x, nhalf, cnt, deg, dcnt);
    k_hist<<<(NE + 255) / 256, 256, 0, stream>>>(ei, deg, rank);
    k_scan1<<<NB_SCAN, 256, 0, stream>>>(deg, off, bsum, dcnt, rankd);
    k_scan2<<<1, 256, 0, stream>>>(bsum, dcnt, dbase);
    k_scan3<<<NB_SCAN, 256, 0, stream>>>(off, bsum, deg, rankd, dbase, perm);
    k_bzpw<<<NN + 512, HIDD, 0, stream>>>(cnt, x, node_idx, emb, W_in, b_in, zb,
                                          Wl1, bl1, Wr1, br1, Wl2, bl2, Wr2, br2, wbT, bias);
    k_fill<<<(NE + 255) / 256, 256, 0, stream>>>(cnt, ei, off, rank, esrc, ea8, ea);

    // ---- layer 1 ----
    k_projmm<<<(NN + 31) / 32, 256, 0, stream>>>(zb, wbT, bias, xl, xr);
    k_gat<<<NN / 8, 256, 0, stream>>>(cnt, perm, off, esrc, ea8, We1, be1, att1, xl, xr, bo1, zb, g1, beta1);

    // ---- layer 2 ----
    k_projmm<<<(NN + 31) / 32, 256, 0, stream>>>(zb, wbT + 256 * HIDD, bias + 256, xl, xr);
    k_gat_last<<<NN / 8, 256, 0, stream>>>(cnt, perm, off, esrc, ea8, We2, be2, att2, xl, xr, bo2, zb,
                                           g2, beta2, W_out, b_out, d_out);
}